// Round 6
// baseline (244.656 us; speedup 1.0000x reference)
//
#include <hip/hip_runtime.h>
#include <hip/hip_bf16.h>
#include <stdint.h>

#define B_   4
#define C_   256
#define C8_  32
#define HW_  4096
#define ROWS_ 320   // 32 Q + 32 K + 256 V composite rows
#define MS_  4      // m-split factor
#define L2E  1.4426950408889634f

typedef __attribute__((ext_vector_type(8)))  short  short8;
typedef __attribute__((ext_vector_type(8)))  ushort us8;
typedef __attribute__((ext_vector_type(16))) float  f32x16;

// ---- workspace layout (bytes) ----
#define WT_OFF    0                            // wbf: bf16 [320 r][256 c]
#define BALL_OFF  (256*320*4)
#define Q_OFF     (BALL_OFF + 1280)
#define KT_OFF    (Q_OFF  + B_*HW_*C8_*2)
#define V_OFF     (KT_OFF + B_*HW_*C8_*2)
#define PACC_OFF  (V_OFF  + B_*C_*HW_*2)
#define LPART_OFF (PACC_OFF + (size_t)MS_*B_*C_*HW_*2)
// total ~44.6 MB

__device__ __forceinline__ ushort f2bf(float f) {
    union { float f; uint32_t u; } v; v.f = f;
    uint32_t u = v.u;
    uint32_t r = u + 0x7fffu + ((u >> 16) & 1u);  // RNE
    return (ushort)(r >> 16);
}
// pack two fp32 -> two bf16 (truncation) in ONE v_perm_b32
__device__ __forceinline__ uint32_t pktr(float lo, float hi) {
    union { float f; uint32_t u; } a, b; a.f = lo; b.f = hi;
    return __builtin_amdgcn_perm(b.u, a.u, 0x07060302u);
}
// Schraudolph exp2: 3 VALU ops, +-3% relative error (centered), exact 0 underflow
__device__ __forceinline__ float fexp2(float s) {
    float y = fmaf(s, 8388608.0f, 1064992506.0f);   // (127-0.043)*2^23
    y = fmaxf(y, 0.0f);
    union { int i; float f; } c; c.i = (int)y;
    return c.f;
}

// ---------------- kernel 1: fold conv into q/k/v weights (bf16) ----------
__global__ __launch_bounds__(256) void k_setup(
    const float* __restrict__ conv_w, const float* __restrict__ conv_b,
    const float* __restrict__ q_w, const float* __restrict__ q_b,
    const float* __restrict__ k_w, const float* __restrict__ k_b,
    const float* __restrict__ v_w, const float* __restrict__ v_b,
    ushort* __restrict__ wbf, float* __restrict__ ball)
{
    int r = blockIdx.x;        // 0..319 composite row
    int c = threadIdx.x;       // 0..255 input channel
    const float* wrow;
    float bias;
    if (r < 32)       { wrow = q_w + r*32;      bias = q_b[r];      }
    else if (r < 64)  { wrow = k_w + (r-32)*32; bias = k_b[r-32];   }
    else              { wrow = v_w + (r-64)*32; bias = v_b[r-64];   }
    float acc = 0.f;
    #pragma unroll
    for (int d = 0; d < 32; ++d) acc += wrow[d] * conv_w[d*C_ + c];
    float scale = (r < 32) ? L2E : 1.0f;       // fold log2(e) into Q
    wbf[r*C_ + c] = f2bf(acc * scale);
    if (c == 0) {
        float bb = bias;
        #pragma unroll
        for (int d = 0; d < 32; ++d) bb += wrow[d] * conv_b[d];
        ball[r] = bb * scale;
    }
}

// ---------------- kernel 2: Q/Kt/V projection via MFMA ----------------
// grid = B * 128 ntiles = 512 blocks, 320 threads (5 waves = 320 rows).
// Wave w: composite rows [w*64, w*64+64), 32 n-cols.
__global__ __launch_bounds__(320) void k_qkv(
    const float* __restrict__ x, const ushort* __restrict__ wbf,
    const float* __restrict__ ball,
    ushort* __restrict__ qg, ushort* __restrict__ ktg, ushort* __restrict__ vg)
{
    int blk = blockIdx.x;
    int b  = blk >> 7;
    int n0 = (blk & 127) * 32;
    int t = threadIdx.x;
    int w = t >> 6, lane = t & 63;
    int l31 = lane & 31, h = lane >> 5;

    f32x16 acc[2];
    acc[0] = (f32x16)(0.f);
    acc[1] = (f32x16)(0.f);

    const float* xb = x + (size_t)b*C_*HW_ + n0 + l31;
    const ushort* wr0 = wbf + (size_t)(w*64 + l31)*C_ + h*8;
    const ushort* wr1 = wr0 + 32*C_;

    #pragma unroll 2
    for (int kc = 0; kc < 16; ++kc) {          // K chunks of 16
        int k0 = kc*16;
        short8 a0 = *(const short8*)(wr0 + k0);
        short8 a1 = *(const short8*)(wr1 + k0);
        const float* xc = xb + (size_t)(k0 + h*8)*HW_;
        union { uint32_t d[4]; short8 s8; } bf;
        #pragma unroll
        for (int j2 = 0; j2 < 4; ++j2) {
            float f0 = xc[(size_t)(2*j2    )*HW_];
            float f1 = xc[(size_t)(2*j2 + 1)*HW_];
            bf.d[j2] = pktr(f0, f1);
        }
        acc[0] = __builtin_amdgcn_mfma_f32_32x32x16_bf16(a0, bf.s8, acc[0], 0, 0, 0);
        acc[1] = __builtin_amdgcn_mfma_f32_32x32x16_bf16(a1, bf.s8, acc[1], 0, 0, 0);
    }

    int n = n0 + l31;
    #pragma unroll
    for (int mi = 0; mi < 2; ++mi) {
        int rowb = w*64 + mi*32;
        if (rowb == 0) {            // Q rows 0..31 -> [B][HW][32], ushort4
            #pragma unroll
            for (int g = 0; g < 4; ++g) {
                int r0 = g*8 + 4*h;
                ushort4 pk;
                pk.x = f2bf(acc[mi][g*4+0] + ball[r0+0]);
                pk.y = f2bf(acc[mi][g*4+1] + ball[r0+1]);
                pk.z = f2bf(acc[mi][g*4+2] + ball[r0+2]);
                pk.w = f2bf(acc[mi][g*4+3] + ball[r0+3]);
                *(ushort4*)(qg + ((size_t)b*HW_ + n)*C8_ + r0) = pk;
            }
        } else if (rowb == 32) {    // K rows -> Kt [B][HW][32], ushort4
            #pragma unroll
            for (int g = 0; g < 4; ++g) {
                int e0 = g*8 + 4*h;
                ushort4 pk;
                pk.x = f2bf(acc[mi][g*4+0] + ball[32+e0+0]);
                pk.y = f2bf(acc[mi][g*4+1] + ball[32+e0+1]);
                pk.z = f2bf(acc[mi][g*4+2] + ball[32+e0+2]);
                pk.w = f2bf(acc[mi][g*4+3] + ball[32+e0+3]);
                *(ushort4*)(ktg + ((size_t)b*HW_ + n)*C8_ + e0) = pk;
            }
        } else {                    // V rows -> [B][C][HW]
            #pragma unroll
            for (int r = 0; r < 16; ++r) {
                int roff = (r & 3) + 8*(r >> 2) + 4*h;
                int c = rowb - 64 + roff;
                vg[((size_t)b*C_ + c)*HW_ + n] = f2bf(acc[mi][r] + ball[rowb + roff]);
            }
        }
    }
}

// ---------------- kernel 3: flash attention, m-split partials ----------------
// grid = 512 blocks (qb fastest for XCD-L2 V locality), 256 thr (4 waves).
// Block: 256 q x 128 c over 1024 keys; wave: 64 q x 128 c.
// MC=128 keys/iter, single-buffered LDS (40 KB), 8 iters, Schraudolph exp2.
__global__ __launch_bounds__(256, 2) void k_attn(
    const ushort* __restrict__ qg, const ushort* __restrict__ ktg,
    const ushort* __restrict__ vg,
    ushort* __restrict__ pacc, float* __restrict__ lpart)
{
    __shared__ ushort v_lds[32*512];   // 32 V frags (cfr*8+ks), 1KB each
    __shared__ ushort kt_lds[8*512];   // 8 Kt frags (kb*2+kseg)

    int blk = blockIdx.x;
    int qb = blk & 15;
    int cs = (blk >> 4) & 1;
    int ms = (blk >> 5) & 3;
    int b  = blk >> 7;
    int t = threadIdx.x;
    int w = t >> 6, lane = t & 63;
    int l31 = lane & 31, h = lane >> 5;
    int qbase = qb*256 + w*64;
    int mbase = ms*1024;

    const ushort* kb_p = ktg + (size_t)b*HW_*C8_;
    const ushort* vb_p = vg  + (size_t)b*C_*HW_ + (size_t)(cs*128 + w*32 + l31)*HW_;

    // Q fragments (B-operand): lane l31 = q, regs = 8 consec e
    short8 qf[2][2];
    #pragma unroll
    for (int qfr = 0; qfr < 2; ++qfr)
        #pragma unroll
        for (int ks = 0; ks < 2; ++ks)
            qf[qfr][ks] = *(const short8*)(qg + ((size_t)b*HW_ + qbase + qfr*32 + l31)*C8_
                                           + ks*16 + h*8);

    f32x16 acc[2][4];
    #pragma unroll
    for (int i = 0; i < 2; ++i)
        #pragma unroll
        for (int j = 0; j < 4; ++j)
            acc[i][j] = (f32x16)(0.f);
    float lsum[2] = {0.f, 0.f};

    for (int it = 0; it < 8; ++it) {
        int m0 = mbase + it*128;
        __syncthreads();   // all waves done reading previous tile
        // stage V: wave w -> c-group w, 8 key-slices (128c x 128m total)
        #pragma unroll
        for (int ks = 0; ks < 8; ++ks) {
            const ushort* src = vb_p + m0 + ks*16 + h*8;
            __builtin_amdgcn_global_load_lds(
                (const __attribute__((address_space(1))) uint32_t*)src,
                (__attribute__((address_space(3))) uint32_t*)&v_lds[(w*8+ks)*512],
                16, 0, 0);
        }
        // stage Kt: wave w -> kb=w, 2 e-slices (128m x 32e total)
        #pragma unroll
        for (int j = 0; j < 2; ++j) {
            const ushort* src = kb_p + (size_t)(m0 + w*32 + l31)*C8_ + j*16 + h*8;
            __builtin_amdgcn_global_load_lds(
                (const __attribute__((address_space(1))) uint32_t*)src,
                (__attribute__((address_space(3))) uint32_t*)&kt_lds[(w*2+j)*512],
                16, 0, 0);
        }
        __syncthreads();   // drain -> tile visible

        #pragma unroll
        for (int kb = 0; kb < 4; ++kb) {
            short8 kt0 = *(const short8*)(&kt_lds[(kb*2+0)*512 + lane*8]);
            short8 kt1 = *(const short8*)(&kt_lds[(kb*2+1)*512 + lane*8]);

            // S tiles -> fast exp2 -> truncated bf16 pairs
            uint32_t up[2][8];
            #pragma unroll
            for (int qfr = 0; qfr < 2; ++qfr) {
                f32x16 s = (f32x16)(0.f);
                s = __builtin_amdgcn_mfma_f32_32x32x16_bf16(kt0, qf[qfr][0], s, 0, 0, 0);
                s = __builtin_amdgcn_mfma_f32_32x32x16_bf16(kt1, qf[qfr][1], s, 0, 0, 0);
                float e[16];
                #pragma unroll
                for (int r = 0; r < 16; ++r) e[r] = fexp2(s[r]);
                float t0 = 0.f, t1 = 0.f;
                #pragma unroll
                for (int r = 0; r < 8; ++r) { t0 += e[2*r]; t1 += e[2*r+1]; }
                lsum[qfr] += t0 + t1;
                #pragma unroll
                for (int i = 0; i < 8; ++i) up[qfr][i] = pktr(e[2*i], e[2*i+1]);
            }

            // build PV B-fragments (lane-half exchange) for this kb
            short8 pf[2][2];   // [qfr][ksub]
            #pragma unroll
            for (int qfr = 0; qfr < 2; ++qfr) {
                uint32_t* u = up[qfr];
                uint32_t bpA = (uint32_t)__shfl_xor((int)(h ? u[0] : u[2]), 32);
                uint32_t bpB = (uint32_t)__shfl_xor((int)(h ? u[1] : u[3]), 32);
                uint32_t bpC = (uint32_t)__shfl_xor((int)(h ? u[4] : u[6]), 32);
                uint32_t bpD = (uint32_t)__shfl_xor((int)(h ? u[5] : u[7]), 32);
                union { uint32_t d[4]; short8 s8; } fe, fo;
                fe.d[0] = h ? bpA : u[0];  fe.d[1] = h ? bpB : u[1];
                fe.d[2] = h ? u[2] : bpA;  fe.d[3] = h ? u[3] : bpB;
                fo.d[0] = h ? bpC : u[4];  fo.d[1] = h ? bpD : u[5];
                fo.d[2] = h ? u[6] : bpC;  fo.d[3] = h ? u[7] : bpD;
                pf[qfr][0] = fe.s8;
                pf[qfr][1] = fo.s8;
            }

            // PV for this kb
            #pragma unroll
            for (int ksub = 0; ksub < 2; ++ksub) {
                int ks = kb*2 + ksub;
                #pragma unroll
                for (int cfr = 0; cfr < 4; ++cfr) {
                    short8 vf = *(const short8*)(&v_lds[(cfr*8 + ks)*512 + lane*8]);
                    acc[0][cfr] = __builtin_amdgcn_mfma_f32_32x32x16_bf16(vf, pf[0][ksub], acc[0][cfr], 0, 0, 0);
                    acc[1][cfr] = __builtin_amdgcn_mfma_f32_32x32x16_bf16(vf, pf[1][ksub], acc[1][cfr], 0, 0, 0);
                }
            }
        }
    }

    // finalize l: add other lane-half's key contributions
    #pragma unroll
    for (int qfr = 0; qfr < 2; ++qfr) {
        union { float f; int i; } cv; cv.f = lsum[qfr];
        cv.i = __shfl_xor(cv.i, 32);
        lsum[qfr] += cv.f;
    }
    if (cs == 0 && h == 0) {
        #pragma unroll
        for (int qfr = 0; qfr < 2; ++qfr)
            lpart[(size_t)(ms*B_ + b)*HW_ + qbase + qfr*32 + l31] = lsum[qfr];
    }

    // store bf16 partial accumulators: [ms][b][qb16][c256][q256]
    size_t pbase = ((size_t)(ms*B_ + b)*16 + qb);
    #pragma unroll
    for (int qfr = 0; qfr < 2; ++qfr) {
        int ql = w*64 + qfr*32 + l31;
        #pragma unroll
        for (int cfr = 0; cfr < 4; ++cfr) {
            #pragma unroll
            for (int r = 0; r < 16; ++r) {
                int c = cs*128 + cfr*32 + (r & 3) + 8*(r >> 2) + 4*h;
                pacc[((pbase*C_ + c) << 8) + ql] = f2bf(acc[qfr][cfr][r]);
            }
        }
    }
}

// ---------------- kernel 4: combine partials + epilogue ----------------
__global__ __launch_bounds__(256) void k_comb(
    const ushort* __restrict__ pacc, const float* __restrict__ lpart,
    const float* __restrict__ x, const float* __restrict__ gamma_p,
    float* __restrict__ out)
{
    int gid = blockIdx.x * 256 + threadIdx.x;   // one thread = 8 elements
    int q8 = gid & 511;
    int c  = (gid >> 9) & 255;
    int b  = gid >> 17;
    int q  = q8 * 8;
    int qt = q >> 8, qq = q & 255;
    size_t base = ((size_t)b*C_ + c)*HW_ + q;

    float sum[8];
    #pragma unroll
    for (int k = 0; k < 8; ++k) sum[k] = 0.f;
    float lt[8];
    #pragma unroll
    for (int k = 0; k < 8; ++k) lt[k] = 0.f;

    #pragma unroll
    for (int ms = 0; ms < MS_; ++ms) {
        const ushort* pp = pacc + ((((size_t)(ms*B_ + b)*16 + qt)*C_ + c) << 8) + qq;
        us8 v = *(const us8*)pp;
        #pragma unroll
        for (int k = 0; k < 8; ++k) {
            union { uint32_t u; float f; } cv; cv.u = ((uint32_t)v[k]) << 16;
            sum[k] += cv.f;
        }
        const float* lp = lpart + (size_t)(ms*B_ + b)*HW_ + q;
        float4 l0 = *(const float4*)lp;
        float4 l1 = *(const float4*)(lp + 4);
        lt[0] += l0.x; lt[1] += l0.y; lt[2] += l0.z; lt[3] += l0.w;
        lt[4] += l1.x; lt[5] += l1.y; lt[6] += l1.z; lt[7] += l1.w;
    }

    float g = gamma_p[0];
    float4 x0 = *(const float4*)(x + base);
    float4 x1 = *(const float4*)(x + base + 4);
    float4 o0, o1;
    o0.x = g*sum[0]/lt[0] + x0.x;  o0.y = g*sum[1]/lt[1] + x0.y;
    o0.z = g*sum[2]/lt[2] + x0.z;  o0.w = g*sum[3]/lt[3] + x0.w;
    o1.x = g*sum[4]/lt[4] + x1.x;  o1.y = g*sum[5]/lt[5] + x1.y;
    o1.z = g*sum[6]/lt[6] + x1.z;  o1.w = g*sum[7]/lt[7] + x1.w;
    *(float4*)(out + base)     = o0;
    *(float4*)(out + base + 4) = o1;
}

extern "C" void kernel_launch(void* const* d_in, const int* in_sizes, int n_in,
                              void* d_out, int out_size, void* d_ws, size_t ws_size,
                              hipStream_t stream)
{
    const float* x      = (const float*)d_in[0];
    const float* conv_w = (const float*)d_in[1];
    const float* conv_b = (const float*)d_in[2];
    const float* q_w    = (const float*)d_in[3];
    const float* q_b    = (const float*)d_in[4];
    const float* k_w    = (const float*)d_in[5];
    const float* k_b    = (const float*)d_in[6];
    const float* v_w    = (const float*)d_in[7];
    const float* v_b    = (const float*)d_in[8];
    const float* gamma  = (const float*)d_in[9];
    float* out = (float*)d_out;

    char* ws = (char*)d_ws;
    ushort* wbf   = (ushort*)(ws + WT_OFF);
    float*  ball  = (float*)(ws + BALL_OFF);
    ushort* qg    = (ushort*)(ws + Q_OFF);
    ushort* ktg   = (ushort*)(ws + KT_OFF);
    ushort* vg    = (ushort*)(ws + V_OFF);
    ushort* pacc  = (ushort*)(ws + PACC_OFF);
    float*  lpart = (float*)(ws + LPART_OFF);

    k_setup<<<ROWS_, 256, 0, stream>>>(conv_w, conv_b, q_w, q_b, k_w, k_b,
                                       v_w, v_b, wbf, ball);
    k_qkv<<<B_*128, 320, 0, stream>>>(x, wbf, ball, qg, ktg, vg);
    k_attn<<<512, 256, 0, stream>>>(qg, ktg, vg, pacc, lpart);
    k_comb<<<(B_*C_*HW_/8 + 255)/256, 256, 0, stream>>>(pacc, lpart, x, gamma, out);
}

// Round 7
// 179.040 us; speedup vs baseline: 1.3665x; 1.3665x over previous
//
#include <hip/hip_runtime.h>
#include <hip/hip_bf16.h>
#include <stdint.h>

#define B_   4
#define C_   256
#define C8_  32
#define HW_  4096
#define ROWS_ 320   // 32 Q + 32 K + 256 V composite rows
#define MS_  4      // m-split factor
#define L2E  1.4426950408889634f

typedef __attribute__((ext_vector_type(8)))  short  short8;
typedef __attribute__((ext_vector_type(8)))  ushort us8;
typedef __attribute__((ext_vector_type(16))) float  f32x16;

// ---- workspace layout (bytes) ----
#define WT_OFF    0                            // wbf: bf16 [320 r][256 c]
#define BALL_OFF  (256*320*4)
#define Q_OFF     (BALL_OFF + 1280)
#define KT_OFF    (Q_OFF  + B_*HW_*C8_*2)
#define V_OFF     (KT_OFF + B_*HW_*C8_*2)
#define PACC_OFF  (V_OFF  + B_*C_*HW_*2)
#define LPART_OFF (PACC_OFF + (size_t)MS_*B_*C_*HW_*2)
// total ~44.6 MB

__device__ __forceinline__ ushort f2bf(float f) {
    union { float f; uint32_t u; } v; v.f = f;
    uint32_t u = v.u;
    uint32_t r = u + 0x7fffu + ((u >> 16) & 1u);  // RNE
    return (ushort)(r >> 16);
}
// pack two fp32 -> two bf16 (truncation) in ONE v_perm_b32
__device__ __forceinline__ uint32_t pktr(float lo, float hi) {
    union { float f; uint32_t u; } a, b; a.f = lo; b.f = hi;
    return __builtin_amdgcn_perm(b.u, a.u, 0x07060302u);
}
// Schraudolph exp2: 3 VALU ops, +-3% relative error (centered), 0 on underflow
__device__ __forceinline__ float fexp2(float s) {
    float y = fmaf(s, 8388608.0f, 1064992506.0f);   // (127-0.043)*2^23
    y = fmaxf(y, 0.0f);
    union { int i; float f; } c; c.i = (int)y;
    return c.f;
}

// ---------------- kernel 1: fold conv into q/k/v weights (bf16) ----------
__global__ __launch_bounds__(256) void k_setup(
    const float* __restrict__ conv_w, const float* __restrict__ conv_b,
    const float* __restrict__ q_w, const float* __restrict__ q_b,
    const float* __restrict__ k_w, const float* __restrict__ k_b,
    const float* __restrict__ v_w, const float* __restrict__ v_b,
    ushort* __restrict__ wbf, float* __restrict__ ball)
{
    int r = blockIdx.x;        // 0..319 composite row
    int c = threadIdx.x;       // 0..255 input channel
    const float* wrow;
    float bias;
    if (r < 32)       { wrow = q_w + r*32;      bias = q_b[r];      }
    else if (r < 64)  { wrow = k_w + (r-32)*32; bias = k_b[r-32];   }
    else              { wrow = v_w + (r-64)*32; bias = v_b[r-64];   }
    float acc = 0.f;
    #pragma unroll
    for (int d = 0; d < 32; ++d) acc += wrow[d] * conv_w[d*C_ + c];
    float scale = (r < 32) ? L2E : 1.0f;       // fold log2(e) into Q
    wbf[r*C_ + c] = f2bf(acc * scale);
    if (c == 0) {
        float bb = bias;
        #pragma unroll
        for (int d = 0; d < 32; ++d) bb += wrow[d] * conv_b[d];
        ball[r] = bb * scale;
    }
}

// ---------------- kernel 2: Q/Kt/V projection via MFMA ----------------
// grid = B * 128 ntiles = 512 blocks, 320 threads (5 waves = 320 rows).
__global__ __launch_bounds__(320) void k_qkv(
    const float* __restrict__ x, const ushort* __restrict__ wbf,
    const float* __restrict__ ball,
    ushort* __restrict__ qg, ushort* __restrict__ ktg, ushort* __restrict__ vg)
{
    int blk = blockIdx.x;
    int b  = blk >> 7;
    int n0 = (blk & 127) * 32;
    int t = threadIdx.x;
    int w = t >> 6, lane = t & 63;
    int l31 = lane & 31, h = lane >> 5;

    f32x16 acc[2];
    acc[0] = (f32x16)(0.f);
    acc[1] = (f32x16)(0.f);

    const float* xb = x + (size_t)b*C_*HW_ + n0 + l31;
    const ushort* wr0 = wbf + (size_t)(w*64 + l31)*C_ + h*8;
    const ushort* wr1 = wr0 + 32*C_;

    #pragma unroll 2
    for (int kc = 0; kc < 16; ++kc) {          // K chunks of 16
        int k0 = kc*16;
        short8 a0 = *(const short8*)(wr0 + k0);
        short8 a1 = *(const short8*)(wr1 + k0);
        const float* xc = xb + (size_t)(k0 + h*8)*HW_;
        union { uint32_t d[4]; short8 s8; } bf;
        #pragma unroll
        for (int j2 = 0; j2 < 4; ++j2) {
            float f0 = xc[(size_t)(2*j2    )*HW_];
            float f1 = xc[(size_t)(2*j2 + 1)*HW_];
            bf.d[j2] = pktr(f0, f1);
        }
        acc[0] = __builtin_amdgcn_mfma_f32_32x32x16_bf16(a0, bf.s8, acc[0], 0, 0, 0);
        acc[1] = __builtin_amdgcn_mfma_f32_32x32x16_bf16(a1, bf.s8, acc[1], 0, 0, 0);
    }

    int n = n0 + l31;
    #pragma unroll
    for (int mi = 0; mi < 2; ++mi) {
        int rowb = w*64 + mi*32;
        if (rowb == 0) {            // Q rows 0..31 -> [B][HW][32], ushort4
            #pragma unroll
            for (int g = 0; g < 4; ++g) {
                int r0 = g*8 + 4*h;
                ushort4 pk;
                pk.x = f2bf(acc[mi][g*4+0] + ball[r0+0]);
                pk.y = f2bf(acc[mi][g*4+1] + ball[r0+1]);
                pk.z = f2bf(acc[mi][g*4+2] + ball[r0+2]);
                pk.w = f2bf(acc[mi][g*4+3] + ball[r0+3]);
                *(ushort4*)(qg + ((size_t)b*HW_ + n)*C8_ + r0) = pk;
            }
        } else if (rowb == 32) {    // K rows -> Kt [B][HW][32], ushort4
            #pragma unroll
            for (int g = 0; g < 4; ++g) {
                int e0 = g*8 + 4*h;
                ushort4 pk;
                pk.x = f2bf(acc[mi][g*4+0] + ball[32+e0+0]);
                pk.y = f2bf(acc[mi][g*4+1] + ball[32+e0+1]);
                pk.z = f2bf(acc[mi][g*4+2] + ball[32+e0+2]);
                pk.w = f2bf(acc[mi][g*4+3] + ball[32+e0+3]);
                *(ushort4*)(ktg + ((size_t)b*HW_ + n)*C8_ + e0) = pk;
            }
        } else {                    // V rows -> [B][C][HW]
            #pragma unroll
            for (int r = 0; r < 16; ++r) {
                int roff = (r & 3) + 8*(r >> 2) + 4*h;
                int c = rowb - 64 + roff;
                vg[((size_t)b*C_ + c)*HW_ + n] = f2bf(acc[mi][r] + ball[rowb + roff]);
            }
        }
    }
}

// ---------------- kernel 3: flash attention, m-split partials ----------------
// grid = 512 blocks: ms=blk&3, cs=bit2, qb=bits[3:6] (stride 8 -> V-sharing
// blocks land on the SAME XCD for L2 reuse), b=bits[7:8]. 256 thr (4 waves).
// Block: 256 q x 128 c over 1024 keys; MC=64, double-buffered frag staging.
// pacc written as raw fragment dump (contiguous 1KB per wave-store).
__global__ __launch_bounds__(256, 2) void k_attn(
    const ushort* __restrict__ qg, const ushort* __restrict__ ktg,
    const ushort* __restrict__ vg,
    ushort* __restrict__ pacc, float* __restrict__ lpart)
{
    __shared__ ushort v_lds[2][16*512];   // 16 V frags (cfr*4+ks), 1KB each
    __shared__ ushort kt_lds[2][4*512];   // 4 Kt frags (kb*2+ks)

    int blk = blockIdx.x;
    int ms = blk & 3;
    int cs = (blk >> 2) & 1;
    int qb = (blk >> 3) & 15;
    int b  = blk >> 7;
    int t = threadIdx.x;
    int w = t >> 6, lane = t & 63;
    int l31 = lane & 31, h = lane >> 5;
    int qbase = qb*256 + w*64;
    int mbase = ms*1024;

    const ushort* kb_p = ktg + (size_t)b*HW_*C8_;
    const ushort* vb_p = vg  + (size_t)b*C_*HW_ + (size_t)cs*128*HW_;

    // Q fragments (B-operand): lane l31 = q, regs = 8 consec e
    short8 qf[2][2];
    #pragma unroll
    for (int qfr = 0; qfr < 2; ++qfr)
        #pragma unroll
        for (int ks = 0; ks < 2; ++ks)
            qf[qfr][ks] = *(const short8*)(qg + ((size_t)b*HW_ + qbase + qfr*32 + l31)*C8_
                                           + ks*16 + h*8);

    f32x16 acc[2][4];
    #pragma unroll
    for (int i = 0; i < 2; ++i)
        #pragma unroll
        for (int j = 0; j < 4; ++j)
            acc[i][j] = (f32x16)(0.f);
    float lsum[2] = {0.f, 0.f};

    #define STAGE(buf, m0)                                                          \
    {                                                                               \
        _Pragma("unroll")                                                           \
        for (int ks = 0; ks < 4; ++ks) {                                            \
            const ushort* src = vb_p + (size_t)(w*32 + l31)*HW_                     \
                                + (m0) + ks*16 + h*8;                               \
            __builtin_amdgcn_global_load_lds(                                       \
                (const __attribute__((address_space(1))) uint32_t*)src,             \
                (__attribute__((address_space(3))) uint32_t*)&v_lds[buf][(w*4+ks)*512], \
                16, 0, 0);                                                          \
        }                                                                           \
        {                                                                           \
            int kb = w >> 1, ks = w & 1;                                            \
            const ushort* src = kb_p + (size_t)((m0) + kb*32 + l31)*C8_             \
                                + ks*16 + h*8;                                      \
            __builtin_amdgcn_global_load_lds(                                       \
                (const __attribute__((address_space(1))) uint32_t*)src,             \
                (__attribute__((address_space(3))) uint32_t*)&kt_lds[buf][w*512],   \
                16, 0, 0);                                                          \
        }                                                                           \
    }

    STAGE(0, mbase)
    __syncthreads();

    int buf = 0;
    for (int it = 0; it < 16; ++it) {
        if (it + 1 < 16) STAGE(buf ^ 1, mbase + (it+1)*64)

        // Kt fragments for this chunk
        short8 ktf[2][2];
        #pragma unroll
        for (int kb = 0; kb < 2; ++kb)
            #pragma unroll
            for (int ks = 0; ks < 2; ++ks)
                ktf[kb][ks] = *(const short8*)(&kt_lds[buf][(kb*2+ks)*512 + lane*8]);

        // S tiles -> fast exp2 (L2E pre-folded) -> truncated bf16 pairs
        uint32_t up[4][8];   // [qfr*2+kb][8]
        #pragma unroll
        for (int qfr = 0; qfr < 2; ++qfr) {
            #pragma unroll
            for (int kb = 0; kb < 2; ++kb) {
                f32x16 s = (f32x16)(0.f);
                s = __builtin_amdgcn_mfma_f32_32x32x16_bf16(ktf[kb][0], qf[qfr][0], s, 0, 0, 0);
                s = __builtin_amdgcn_mfma_f32_32x32x16_bf16(ktf[kb][1], qf[qfr][1], s, 0, 0, 0);
                float e[16];
                #pragma unroll
                for (int r = 0; r < 16; ++r) e[r] = fexp2(s[r]);
                float t0 = 0.f, t1 = 0.f;
                #pragma unroll
                for (int r = 0; r < 8; ++r) { t0 += e[2*r]; t1 += e[2*r+1]; }
                lsum[qfr] += t0 + t1;
                #pragma unroll
                for (int i = 0; i < 8; ++i)
                    up[qfr*2+kb][i] = pktr(e[2*i], e[2*i+1]);
            }
        }

        // Build PV B-fragments: lane-half exchange
        short8 pf[2][4];   // [qfr][ks 0..3]
        #pragma unroll
        for (int qfr = 0; qfr < 2; ++qfr) {
            #pragma unroll
            for (int kb = 0; kb < 2; ++kb) {
                uint32_t* u = up[qfr*2+kb];
                uint32_t bpA = (uint32_t)__shfl_xor((int)(h ? u[0] : u[2]), 32);
                uint32_t bpB = (uint32_t)__shfl_xor((int)(h ? u[1] : u[3]), 32);
                uint32_t bpC = (uint32_t)__shfl_xor((int)(h ? u[4] : u[6]), 32);
                uint32_t bpD = (uint32_t)__shfl_xor((int)(h ? u[5] : u[7]), 32);
                union { uint32_t d[4]; short8 s8; } fe, fo;
                fe.d[0] = h ? bpA : u[0];  fe.d[1] = h ? bpB : u[1];
                fe.d[2] = h ? u[2] : bpA;  fe.d[3] = h ? u[3] : bpB;
                fo.d[0] = h ? bpC : u[4];  fo.d[1] = h ? bpD : u[5];
                fo.d[2] = h ? u[6] : bpC;  fo.d[3] = h ? u[7] : bpD;
                pf[qfr][kb*2 + 0] = fe.s8;
                pf[qfr][kb*2 + 1] = fo.s8;
            }
        }

        // PV: acc[qfr][cfr] += V(cfr,ks) * P(qfr,ks)
        #pragma unroll
        for (int ks = 0; ks < 4; ++ks) {
            #pragma unroll
            for (int cfr = 0; cfr < 4; ++cfr) {
                short8 vf = *(const short8*)(&v_lds[buf][(cfr*4+ks)*512 + lane*8]);
                acc[0][cfr] = __builtin_amdgcn_mfma_f32_32x32x16_bf16(vf, pf[0][ks], acc[0][cfr], 0, 0, 0);
                acc[1][cfr] = __builtin_amdgcn_mfma_f32_32x32x16_bf16(vf, pf[1][ks], acc[1][cfr], 0, 0, 0);
            }
        }
        __syncthreads();
        buf ^= 1;
    }

    // finalize l: add other lane-half's key contributions
    #pragma unroll
    for (int qfr = 0; qfr < 2; ++qfr) {
        union { float f; int i; } cv; cv.f = lsum[qfr];
        cv.i = __shfl_xor(cv.i, 32);
        lsum[qfr] += cv.f;
    }
    if (cs == 0 && h == 0) {
        #pragma unroll
        for (int qfr = 0; qfr < 2; ++qfr)
            lpart[(size_t)(ms*B_ + b)*HW_ + qbase + qfr*32 + l31] = lsum[qfr];
    }

    // store pacc as raw fragment dump: per (qfr,cfr) the wave writes 2x1KB
    // contiguous (lane*16B) -> zero scatter, full-line HBM writes.
    int blkl = ((ms*B_ + b)*16 + qb)*2 + cs;
    #pragma unroll
    for (int qfr = 0; qfr < 2; ++qfr) {
        #pragma unroll
        for (int cfr = 0; cfr < 4; ++cfr) {
            union { uint32_t d[8]; us8 hlf[2]; } pk;
            #pragma unroll
            for (int i = 0; i < 8; ++i)
                pk.d[i] = pktr(acc[qfr][cfr][2*i], acc[qfr][cfr][2*i+1]);
            ushort* dst = pacc + ((size_t)(blkl*32 + (w*2 + qfr)*4 + cfr) << 10);
            *(us8*)(dst + lane*8)       = pk.hlf[0];
            *(us8*)(dst + 512 + lane*8) = pk.hlf[1];
        }
    }
    #undef STAGE
}

// ---------------- kernel 4: combine fragment partials + epilogue ----------
// thread bits: [4:0]=l31(q), [5]=h, [7:6]=cfr, [8]=qfr, [10:9]=w, [11]=cs,
// [15:12]=qb, [17:16]=b. Each thread: 16 channels x 1 q, summed over ms.
__global__ __launch_bounds__(256) void k_comb(
    const ushort* __restrict__ pacc, const float* __restrict__ lpart,
    const float* __restrict__ x, const float* __restrict__ gamma_p,
    float* __restrict__ out)
{
    int gid = blockIdx.x * 256 + threadIdx.x;
    int l31 = gid & 31;
    int h   = (gid >> 5) & 1;
    int cfr = (gid >> 6) & 3;
    int qfr = (gid >> 8) & 1;
    int w   = (gid >> 9) & 3;
    int cs  = (gid >> 11) & 1;
    int qb  = (gid >> 12) & 15;
    int b   = (gid >> 16) & 3;

    int q = qb*256 + w*64 + qfr*32 + l31;
    int frag = (w*2 + qfr)*4 + cfr;
    int lane = h*32 + l31;

    float sum[16];
    #pragma unroll
    for (int k = 0; k < 16; ++k) sum[k] = 0.f;
    float lt = 0.f;

    #pragma unroll
    for (int ms = 0; ms < MS_; ++ms) {
        int blkl = ((ms*B_ + b)*16 + qb)*2 + cs;
        const ushort* pp = pacc + ((size_t)(blkl*32 + frag) << 10) + lane*8;
        us8 a0 = *(const us8*)pp;
        us8 a1 = *(const us8*)(pp + 512);
        #pragma unroll
        for (int k = 0; k < 8; ++k) {
            union { uint32_t u; float f; } cv;
            cv.u = ((uint32_t)a0[k]) << 16;  sum[k]   += cv.f;
            cv.u = ((uint32_t)a1[k]) << 16;  sum[k+8] += cv.f;
        }
        lt += lpart[(size_t)(ms*B_ + b)*HW_ + q];
    }

    float g = gamma_p[0];
    float rl = g / lt;
    const float* xb = x + (size_t)b*C_*HW_ + q;
    float* ob = out + (size_t)b*C_*HW_ + q;
    #pragma unroll
    for (int k = 0; k < 16; ++k) {
        int c = cs*128 + cfr*32 + (k & 3) + 8*(k >> 2) + 4*h;
        size_t idx = (size_t)c*HW_;
        ob[idx] = sum[k]*rl + xb[idx];
    }
}

extern "C" void kernel_launch(void* const* d_in, const int* in_sizes, int n_in,
                              void* d_out, int out_size, void* d_ws, size_t ws_size,
                              hipStream_t stream)
{
    const float* x      = (const float*)d_in[0];
    const float* conv_w = (const float*)d_in[1];
    const float* conv_b = (const float*)d_in[2];
    const float* q_w    = (const float*)d_in[3];
    const float* q_b    = (const float*)d_in[4];
    const float* k_w    = (const float*)d_in[5];
    const float* k_b    = (const float*)d_in[6];
    const float* v_w    = (const float*)d_in[7];
    const float* v_b    = (const float*)d_in[8];
    const float* gamma  = (const float*)d_in[9];
    float* out = (float*)d_out;

    char* ws = (char*)d_ws;
    ushort* wbf   = (ushort*)(ws + WT_OFF);
    float*  ball  = (float*)(ws + BALL_OFF);
    ushort* qg    = (ushort*)(ws + Q_OFF);
    ushort* ktg   = (ushort*)(ws + KT_OFF);
    ushort* vg    = (ushort*)(ws + V_OFF);
    ushort* pacc  = (ushort*)(ws + PACC_OFF);
    float*  lpart = (float*)(ws + LPART_OFF);

    k_setup<<<ROWS_, 256, 0, stream>>>(conv_w, conv_b, q_w, q_b, k_w, k_b,
                                       v_w, v_b, wbf, ball);
    k_qkv<<<B_*128, 320, 0, stream>>>(x, wbf, ball, qg, ktg, vg);
    k_attn<<<512, 256, 0, stream>>>(qg, ktg, vg, pacc, lpart);
    k_comb<<<(B_*HW_*C_/16)/256, 256, 0, stream>>>(pacc, lpart, x, gamma, out);
}